// Round 1
// baseline (3444.991 us; speedup 1.0000x reference)
//
#include <hip/hip_runtime.h>
#include <stdint.h>

// Problem constants
constexpr int NB = 32;     // batch
constexpr int NS = 64;     // src len
constexpr int NT = 64;     // trg len
constexpr int NV = 32000;  // vocab
constexpr int NE = 256;    // embed dim
constexpr int NH = 512;    // hidden

typedef unsigned short u16;
typedef short bf16x8 __attribute__((ext_vector_type(8)));
typedef float f32x4  __attribute__((ext_vector_type(4)));

__device__ inline u16 f2bf(float f){
  unsigned int u = __float_as_uint(f);
  u = u + 0x7FFFu + ((u >> 16) & 1u);   // round-to-nearest-even
  return (u16)(u >> 16);
}

// ---------------------------------------------------------------- zero init
__global__ void zero_init(float* __restrict__ out, float* __restrict__ hA){
  int i = blockIdx.x * blockDim.x + threadIdx.x;
  int stride = gridDim.x * blockDim.x;
  // out[:, 0, :] = 0
  for (int idx = i; idx < NB * NV; idx += stride){
    int b = idx / NV, v = idx % NV;
    out[(size_t)b * NT * NV + v] = 0.f;
  }
  // h0 = 0
  for (int idx = i; idx < NB * NH; idx += stride) hA[idx] = 0.f;
}

// ---------------------------------------------------------------- f32 -> bf16
__global__ void cvt_f32_bf16(const float* __restrict__ in, u16* __restrict__ out, int n4){
  int i = blockIdx.x * blockDim.x + threadIdx.x;
  int stride = gridDim.x * blockDim.x;
  for (int idx = i; idx < n4; idx += stride){
    float4 v = ((const float4*)in)[idx];
    unsigned int lo = (unsigned int)f2bf(v.x) | ((unsigned int)f2bf(v.y) << 16);
    unsigned int hi = (unsigned int)f2bf(v.z) | ((unsigned int)f2bf(v.w) << 16);
    *(uint2*)(out + (size_t)idx * 4) = make_uint2(lo, hi);
  }
}

// ---------------------------------------------------------------- embedding gather (time-major rows m = t*NB + b)
__global__ void embed_k(const int* __restrict__ idx, int ld, int tcount,
                        const float* __restrict__ emb, u16* __restrict__ xbf){
  int tid = blockIdx.x * blockDim.x + threadIdx.x;
  int n4 = tcount * NB * (NE / 4);
  if (tid >= n4) return;
  int e4 = tid & (NE/4 - 1);      // NE/4 = 64
  int m  = tid >> 6;
  int t = m / NB, b = m % NB;
  int row = idx[b * ld + t];
  float4 v = ((const float4*)(emb + (size_t)row * NE))[e4];
  unsigned int lo = (unsigned int)f2bf(v.x) | ((unsigned int)f2bf(v.y) << 16);
  unsigned int hi = (unsigned int)f2bf(v.z) | ((unsigned int)f2bf(v.w) << 16);
  *(uint2*)(xbf + (size_t)m * NE + e4 * 4) = make_uint2(lo, hi);
}

// ---------------------------------------------------------------- bf16 MFMA GEMM: C = A(MxK) * B(NxK)^T + bias
// 128x128 tile, BK=32, 4 waves each 64x64 (4x4 frags of 16x16x32).
// SCATTER: row m = t*NB+b -> out[b, t+1, col]  (fc projection)
// else   : C[row * Nld + col]                  (gi precompute)
template<int KDIM, bool SCATTER>
__global__ __launch_bounds__(256) void gemm_bt(const u16* __restrict__ A,
                                               const u16* __restrict__ Bm,
                                               const float* __restrict__ bias,
                                               float* __restrict__ C,
                                               int M, int Nld)
{
  __shared__ u16 As[128 * 32];
  __shared__ u16 Bs[128 * 32];
  const int tid  = threadIdx.x;
  const int lane = tid & 63;
  const int w = tid >> 6, wm = w >> 1, wn = w & 1;
  const int m0 = blockIdx.y * 128, n0 = blockIdx.x * 128;
  f32x4 acc[4][4] = {};

  for (int k0 = 0; k0 < KDIM; k0 += 32){
    __syncthreads();
    #pragma unroll
    for (int it = 0; it < 2; ++it){
      int off = it * 4096 + tid * 16;      // byte offset into 8KB tile
      int r = off >> 6, cb = off & 63;     // tile row, byte within 64B row
      uint4 av = make_uint4(0,0,0,0);
      if (m0 + r < M)
        av = *(const uint4*)((const char*)A + ((size_t)(m0 + r) * KDIM + k0) * 2 + cb);
      *(uint4*)((char*)As + off) = av;
      uint4 bv = *(const uint4*)((const char*)Bm + ((size_t)(n0 + r) * KDIM + k0) * 2 + cb);
      *(uint4*)((char*)Bs + off) = bv;
    }
    __syncthreads();
    bf16x8 af[4], bfr[4];
    #pragma unroll
    for (int i = 0; i < 4; ++i)
      af[i] = *(const bf16x8*)((const char*)As + (wm*64 + i*16 + (lane & 15)) * 64 + (lane >> 4) * 16);
    #pragma unroll
    for (int j = 0; j < 4; ++j)
      bfr[j] = *(const bf16x8*)((const char*)Bs + (wn*64 + j*16 + (lane & 15)) * 64 + (lane >> 4) * 16);
    #pragma unroll
    for (int i = 0; i < 4; ++i)
      #pragma unroll
      for (int j = 0; j < 4; ++j)
        acc[i][j] = __builtin_amdgcn_mfma_f32_16x16x32_bf16(af[i], bfr[j], acc[i][j], 0, 0, 0);
  }

  #pragma unroll
  for (int i = 0; i < 4; ++i){
    #pragma unroll
    for (int j = 0; j < 4; ++j){
      int col = n0 + wn*64 + j*16 + (lane & 15);
      float bv = bias[col];
      #pragma unroll
      for (int rr = 0; rr < 4; ++rr){
        int row = m0 + wm*64 + i*16 + (lane >> 4) * 4 + rr;
        if (row < M){
          float val = acc[i][j][rr] + bv;
          if (SCATTER){
            int t = row >> 5, b = row & 31;  // m = t*NB + b, NB=32
            C[(size_t)b * (NT * NV) + (size_t)(t + 1) * NV + col] = val;
          } else {
            C[(size_t)row * Nld + col] = val;
          }
        }
      }
    }
  }
}

// ---------------------------------------------------------------- GRU recurrence step (fp32)
// grid = 128 wgs, wg owns 4 hidden units. 256 thr: tid = half*128 + b*4 + jj.
// Each thread: 3 gate dots over half of K (256), then LDS reduce + gate math.
__global__ __launch_bounds__(256) void gru_step(const float* __restrict__ h_in,
                                                float* __restrict__ h_out,
                                                const float* __restrict__ gi,   // (NB, 3*NH) for this t
                                                const float* __restrict__ W_hh, // (3*NH, NH)
                                                const float* __restrict__ b_hh,
                                                u16* __restrict__ h2bf)         // (NB, NH) or null
{
  const int tid = threadIdx.x;
  const int kh = tid >> 7;          // k-half
  const int p  = tid & 127;
  const int b  = p >> 2;
  const int jj = p & 3;
  const int j  = blockIdx.x * 4 + jj;

  f32x4 a0 = {0,0,0,0}, a1 = {0,0,0,0}, a2 = {0,0,0,0};
  const f32x4* hp = (const f32x4*)(h_in + (size_t)b * NH) + kh * 64;
  const f32x4* w0 = (const f32x4*)(W_hh + ((size_t)(0*NH + j)) * NH) + kh * 64;
  const f32x4* w1 = (const f32x4*)(W_hh + ((size_t)(1*NH + j)) * NH) + kh * 64;
  const f32x4* w2 = (const f32x4*)(W_hh + ((size_t)(2*NH + j)) * NH) + kh * 64;
  #pragma unroll 8
  for (int k = 0; k < 64; ++k){
    f32x4 hv = hp[k];
    a0 += hv * w0[k];
    a1 += hv * w1[k];
    a2 += hv * w2[k];
  }
  __shared__ float red[128][2][3];
  red[p][kh][0] = a0[0] + a0[1] + a0[2] + a0[3];
  red[p][kh][1] = a1[0] + a1[1] + a1[2] + a1[3];
  red[p][kh][2] = a2[0] + a2[1] + a2[2] + a2[3];
  __syncthreads();
  if (kh == 0){
    float ghr = red[p][0][0] + red[p][1][0] + b_hh[0*NH + j];
    float ghz = red[p][0][1] + red[p][1][1] + b_hh[1*NH + j];
    float ghn = red[p][0][2] + red[p][1][2] + b_hh[2*NH + j];
    const float* gib = gi + (size_t)b * (3 * NH);
    float ir  = gib[0*NH + j];
    float iz  = gib[1*NH + j];
    float inn = gib[2*NH + j];
    float r = 1.f / (1.f + expf(-(ir + ghr)));
    float z = 1.f / (1.f + expf(-(iz + ghz)));
    float n = tanhf(inn + r * ghn);
    float hprev = h_in[(size_t)b * NH + j];
    float hnew  = (1.f - z) * n + z * hprev;
    h_out[(size_t)b * NH + j] = hnew;
    if (h2bf) h2bf[(size_t)b * NH + j] = f2bf(hnew);
  }
}

// ---------------------------------------------------------------- launcher
extern "C" void kernel_launch(void* const* d_in, const int* in_sizes, int n_in,
                              void* d_out, int out_size, void* d_ws, size_t ws_size,
                              hipStream_t stream)
{
  const int*   src      = (const int*)  d_in[0];
  const int*   trg      = (const int*)  d_in[1];
  const float* emb_enc  = (const float*)d_in[2];
  const float* W_ih_enc = (const float*)d_in[3];
  const float* W_hh_enc = (const float*)d_in[4];
  const float* b_ih_enc = (const float*)d_in[5];
  const float* b_hh_enc = (const float*)d_in[6];
  const float* emb_dec  = (const float*)d_in[7];
  const float* W_ih_dec = (const float*)d_in[8];
  const float* W_hh_dec = (const float*)d_in[9];
  const float* b_ih_dec = (const float*)d_in[10];
  const float* b_hh_dec = (const float*)d_in[11];
  const float* fc_W     = (const float*)d_in[12];
  const float* fc_b     = (const float*)d_in[13];
  float* out = (float*)d_out;

  char* ws = (char*)d_ws;
  size_t o = 0;
  auto alloc = [&](size_t bytes){ size_t r = o; o += (bytes + 255) & ~(size_t)255; return r; };
  u16*   xenc  = (u16*)  (ws + alloc((size_t)NS * NB * NE * 2));
  u16*   xdec  = (u16*)  (ws + alloc((size_t)(NT-1) * NB * NE * 2));
  u16*   wihe  = (u16*)  (ws + alloc((size_t)3 * NH * NE * 2));
  u16*   wihd  = (u16*)  (ws + alloc((size_t)3 * NH * NE * 2));
  u16*   fcWbf = (u16*)  (ws + alloc((size_t)NV * NH * 2));
  float* gie   = (float*)(ws + alloc((size_t)NS * NB * 3 * NH * 4));
  float* gid   = (float*)(ws + alloc((size_t)(NT-1) * NB * 3 * NH * 4));
  float* hA    = (float*)(ws + alloc((size_t)NB * NH * 4));
  float* hB    = (float*)(ws + alloc((size_t)NB * NH * 4));
  u16*   Hall  = (u16*)  (ws + alloc((size_t)(NT-1) * NB * NH * 2));

  zero_init<<<256, 256, 0, stream>>>(out, hA);
  cvt_f32_bf16<<<512, 256, 0, stream>>>(W_ih_enc, wihe, 3*NH*NE/4);
  cvt_f32_bf16<<<512, 256, 0, stream>>>(W_ih_dec, wihd, 3*NH*NE/4);
  cvt_f32_bf16<<<2048, 256, 0, stream>>>(fc_W, fcWbf, NV*NH/4);
  embed_k<<<(NS*NB*64 + 255)/256, 256, 0, stream>>>(src, NS, NS, emb_enc, xenc);
  embed_k<<<((NT-1)*NB*64 + 255)/256, 256, 0, stream>>>(trg, NT, NT-1, emb_dec, xdec);

  // gi = x @ W_ih^T + b_ih  (time-major rows)
  gemm_bt<NE, false><<<dim3(3*NH/128, 16), 256, 0, stream>>>(xenc, wihe, b_ih_enc, gie, NS*NB, 3*NH);
  gemm_bt<NE, false><<<dim3(3*NH/128, 16), 256, 0, stream>>>(xdec, wihd, b_ih_dec, gid, (NT-1)*NB, 3*NH);

  // sequential GRU recurrence (fp32)
  float* hin = hA; float* hout = hB;
  for (int t = 0; t < NS; ++t){
    gru_step<<<128, 256, 0, stream>>>(hin, hout, gie + (size_t)t*NB*3*NH, W_hh_enc, b_hh_enc, (u16*)nullptr);
    float* tmp = hin; hin = hout; hout = tmp;
  }
  for (int t = 0; t < NT-1; ++t){
    gru_step<<<128, 256, 0, stream>>>(hin, hout, gid + (size_t)t*NB*3*NH, W_hh_dec, b_hh_dec, Hall + (size_t)t*NB*NH);
    float* tmp = hin; hin = hout; hout = tmp;
  }

  // logits = h2 @ fc_W^T + fc_b, scattered to out[b, t+1, :]
  gemm_bt<NH, true><<<dim3(NV/128, 16), 256, 0, stream>>>(Hall, fcWbf, fc_b, out, (NT-1)*NB, 0);
}

// Round 3
// 1400.400 us; speedup vs baseline: 2.4600x; 2.4600x over previous
//
#include <hip/hip_runtime.h>
#include <stdint.h>

constexpr int NB = 32, NS = 64, NT = 64, NV = 32000, NE = 256, NH = 512;
constexpr int RG = 64;          // recurrence workgroups
constexpr int HU = 8;           // hidden units per wg
constexpr int GR = 3 * HU;      // 24 gate rows per wg
constexpr int TSTEPS = NS + NT - 1;   // 127

typedef unsigned short u16;
typedef short bf16x8 __attribute__((ext_vector_type(8)));
typedef float f32x4  __attribute__((ext_vector_type(4)));

__device__ inline u16 f2bf(float f){
  unsigned int u = __float_as_uint(f);
  u = u + 0x7FFFu + ((u >> 16) & 1u);
  return (u16)(u >> 16);
}
__device__ inline float bf2f(u16 h){ return __uint_as_float(((unsigned)h) << 16); }

__device__ inline void gload_lds16(const u16* g, u16* l){
  __builtin_amdgcn_global_load_lds((const __attribute__((address_space(1))) void*)g,
                                   (__attribute__((address_space(3))) void*)l, 16, 0, 0);
}

// ---------------------------------------------------------------- zero init (out row 0, pad rows)
__global__ void zero_init(float* __restrict__ out, u16* __restrict__ xdecpad, u16* __restrict__ hallpad){
  int i = blockIdx.x * blockDim.x + threadIdx.x, st = gridDim.x * blockDim.x;
  for (int idx = i; idx < NB * NV; idx += st){
    int b = idx / NV, v = idx - b * NV;
    out[(size_t)b * NT * NV + v] = 0.f;
  }
  for (int idx = i; idx < 32 * NE; idx += st) xdecpad[idx] = 0;
  for (int idx = i; idx < 32 * NH; idx += st) hallpad[idx] = 0;
}

// ---------------------------------------------------------------- f32 -> bf16
__global__ void cvt_f32_bf16(const float* __restrict__ in, u16* __restrict__ out, int n4){
  int i = blockIdx.x * blockDim.x + threadIdx.x, st = gridDim.x * blockDim.x;
  for (int idx = i; idx < n4; idx += st){
    float4 v = ((const float4*)in)[idx];
    unsigned lo = (unsigned)f2bf(v.x) | ((unsigned)f2bf(v.y) << 16);
    unsigned hi = (unsigned)f2bf(v.z) | ((unsigned)f2bf(v.w) << 16);
    *(uint2*)(out + (size_t)idx * 4) = make_uint2(lo, hi);
  }
}

// ---------------------------------------------------------------- f32 -> (bf16 hi, bf16 lo)
__global__ void cvt_hilo(const float* __restrict__ in, u16* __restrict__ hi, u16* __restrict__ lo, int n){
  int i = blockIdx.x * blockDim.x + threadIdx.x, st = gridDim.x * blockDim.x;
  for (int idx = i; idx < n; idx += st){
    float w = in[idx];
    u16 h = f2bf(w);
    hi[idx] = h;
    lo[idx] = f2bf(w - bf2f(h));
  }
}

// ---------------------------------------------------------------- embedding gather (rows m = t*NB + b)
__global__ void embed_k(const int* __restrict__ idx, int ld, int tcount,
                        const float* __restrict__ emb, u16* __restrict__ xbf){
  int tid = blockIdx.x * blockDim.x + threadIdx.x;
  int n4 = tcount * NB * (NE / 4);
  if (tid >= n4) return;
  int e4 = tid & (NE/4 - 1);
  int m  = tid >> 6;
  int t = m / NB, b = m % NB;
  int row = idx[b * ld + t];
  float4 v = ((const float4*)(emb + (size_t)row * NE))[e4];
  unsigned lo = (unsigned)f2bf(v.x) | ((unsigned)f2bf(v.y) << 16);
  unsigned hi = (unsigned)f2bf(v.z) | ((unsigned)f2bf(v.w) << 16);
  *(uint2*)(xbf + (size_t)m * NE + e4 * 4) = make_uint2(lo, hi);
}

// ---------------------------------------------------------------- bf16 MFMA GEMM: C = A(MxK) * B(NxK)^T + bias
// 128x128 tile, BK=32, global_load_lds staging (no guards: M padded to mult of 128).
// 1-D grid with chunked XCD swizzle; wg = nblk*16 + mblk (consecutive wgs share B panel).
template<int KDIM, bool SCATTER>
__global__ __launch_bounds__(256) void gemm_bt(const u16* __restrict__ A,
                                               const u16* __restrict__ Bm,
                                               const float* __restrict__ bias,
                                               float* __restrict__ C,
                                               int Mstore, int Nld)
{
  __shared__ u16 As[128 * 32];
  __shared__ u16 Bs[128 * 32];
  const int id = blockIdx.x;
  const int q = gridDim.x >> 3;
  const int wg = (id & 7) * q + (id >> 3);
  const int m0 = (wg & 15) * 128, n0 = (wg >> 4) * 128;
  const int tid  = threadIdx.x;
  const int lane = tid & 63;
  const int w = tid >> 6, wm = w >> 1, wn = w & 1;
  f32x4 acc[4][4] = {};

  const int sr = w * 16 + (lane >> 2);     // staging row 0..63
  const int sc = (lane & 3) * 8;           // element col (16B)
  const u16* aS = A  + (size_t)(m0 + sr) * KDIM + sc;
  const u16* bS = Bm + (size_t)(n0 + sr) * KDIM + sc;
  u16* asl = As + w * 16 * 32;
  u16* bsl = Bs + w * 16 * 32;

  for (int k0 = 0; k0 < KDIM; k0 += 32){
    gload_lds16(aS + k0, asl);
    gload_lds16(aS + (size_t)64 * KDIM + k0, asl + 64 * 32);
    gload_lds16(bS + k0, bsl);
    gload_lds16(bS + (size_t)64 * KDIM + k0, bsl + 64 * 32);
    __syncthreads();
    bf16x8 af[4], bfr[4];
    #pragma unroll
    for (int i = 0; i < 4; ++i)
      af[i] = *(const bf16x8*)((const char*)As + (wm*64 + i*16 + (lane & 15)) * 64 + (lane >> 4) * 16);
    #pragma unroll
    for (int j = 0; j < 4; ++j)
      bfr[j] = *(const bf16x8*)((const char*)Bs + (wn*64 + j*16 + (lane & 15)) * 64 + (lane >> 4) * 16);
    #pragma unroll
    for (int i = 0; i < 4; ++i)
      #pragma unroll
      for (int j = 0; j < 4; ++j)
        acc[i][j] = __builtin_amdgcn_mfma_f32_16x16x32_bf16(af[i], bfr[j], acc[i][j], 0, 0, 0);
    __syncthreads();
  }

  #pragma unroll
  for (int i = 0; i < 4; ++i){
    #pragma unroll
    for (int j = 0; j < 4; ++j){
      int col = n0 + wn*64 + j*16 + (lane & 15);
      float bv = bias[col];
      #pragma unroll
      for (int rr = 0; rr < 4; ++rr){
        int row = m0 + wm*64 + i*16 + (lane >> 4) * 4 + rr;
        float val = acc[i][j][rr] + bv;
        if (SCATTER){
          if (row < Mstore){
            int t = row >> 5, b = row & 31;
            C[(size_t)b * (NT * NV) + (size_t)(t + 1) * NV + col] = val;
          }
        } else {
          C[(size_t)row * Nld + col] = val;
        }
      }
    }
  }
}

// ---------------------------------------------------------------- persistent GRU recurrence
// 64 wgs x 256 thr. Each wg owns 8 hidden units (24 gate rows) of W_hh in LDS (bf16 hi+lo).
// Per step: stage h (bf16 hi/lo, double-buffered global) -> compensated MFMA -> gates fp32
// -> write h -> grid spin-barrier.
__global__ __launch_bounds__(256) void gru_rec(
    const u16* __restrict__ WhiE, const u16* __restrict__ WloE,
    const u16* __restrict__ WhiD, const u16* __restrict__ WloD,
    const float* __restrict__ bhhE, const float* __restrict__ bhhD,
    const float* __restrict__ gie, const float* __restrict__ gid,
    u16* __restrict__ HhiG0, u16* __restrict__ HloG0,
    u16* __restrict__ HhiG1, u16* __restrict__ HloG1,
    u16* __restrict__ Hall, unsigned* __restrict__ bar)
{
  extern __shared__ char smem[];
  u16* Whi = (u16*)smem;              // [24][512] swizzled ( garbage-read slack into next region )
  u16* Wlo = Whi + GR * NH;
  u16* Hhi = Wlo + GR * NH;           // [32][512] swizzled
  u16* Hlo = Hhi + NB * NH;
  float* GH = (float*)(Hlo + NB * NH);// [24][32]

  const int tid  = threadIdx.x;
  const int lane = tid & 63;
  const int w    = tid >> 6;          // 0..3
  const int mt   = w >> 1, nt = w & 1;
  const int j0   = blockIdx.x * HU;
  unsigned ls = 0;

  // ---- stage encoder W slice (hi/lo), zero h LDS
  for (int c = tid; c < GR * 64; c += 256){
    int r = c >> 6, c16 = c & 63;
    int grow = (r >> 3) * NH + j0 + (r & 7);
    int d = (r << 10) | ((c16 * 16) ^ ((r & 7) << 4));
    *(uint4*)((char*)Whi + d) = *(const uint4*)(WhiE + (size_t)grow * NH + c16 * 8);
    *(uint4*)((char*)Wlo + d) = *(const uint4*)(WloE + (size_t)grow * NH + c16 * 8);
  }
  for (int c = tid; c < NB * 64; c += 256){
    int r = c >> 6, c16 = c & 63;
    int d = (r << 10) | ((c16 * 16) ^ ((r & 7) << 4));
    *(uint4*)((char*)Hhi + d) = make_uint4(0,0,0,0);
    *(uint4*)((char*)Hlo + d) = make_uint4(0,0,0,0);
  }
  __syncthreads();

  for (int t = 0; t < TSTEPS; ++t){
    const bool dec = (t >= NS);
    if (t == NS){
      for (int c = tid; c < GR * 64; c += 256){
        int r = c >> 6, c16 = c & 63;
        int grow = (r >> 3) * NH + j0 + (r & 7);
        int d = (r << 10) | ((c16 * 16) ^ ((r & 7) << 4));
        *(uint4*)((char*)Whi + d) = *(const uint4*)(WhiD + (size_t)grow * NH + c16 * 8);
        *(uint4*)((char*)Wlo + d) = *(const uint4*)(WloD + (size_t)grow * NH + c16 * 8);
      }
      __syncthreads();
    }
    const float* bhh  = dec ? bhhD : bhhE;
    const float* gi_t = dec ? (gid + (size_t)(t - NS) * NB * 3 * NH)
                            : (gie + (size_t)t * NB * 3 * NH);

    // ---- gh = W_slice(24x512) . h(32x512)^T via compensated bf16 MFMA
    f32x4 acc = {0.f, 0.f, 0.f, 0.f};
    #pragma unroll 4
    for (int kk = 0; kk < 16; ++kk){
      const int bc = kk * 64 + ((lane >> 4) << 4);
      const int ra = mt * 16 + (lane & 15);     // rows 24..31 read harmless garbage (in-bounds LDS)
      const int rb = nt * 16 + (lane & 15);
      bf16x8 ah = *(const bf16x8*)((char*)Whi + ((ra << 10) | (bc ^ ((ra & 7) << 4))));
      bf16x8 al = *(const bf16x8*)((char*)Wlo + ((ra << 10) | (bc ^ ((ra & 7) << 4))));
      bf16x8 bh = *(const bf16x8*)((char*)Hhi + ((rb << 10) | (bc ^ ((rb & 7) << 4))));
      bf16x8 bl = *(const bf16x8*)((char*)Hlo + ((rb << 10) | (bc ^ ((rb & 7) << 4))));
      acc = __builtin_amdgcn_mfma_f32_16x16x32_bf16(ah, bh, acc, 0, 0, 0);
      acc = __builtin_amdgcn_mfma_f32_16x16x32_bf16(al, bh, acc, 0, 0, 0);
      acc = __builtin_amdgcn_mfma_f32_16x16x32_bf16(ah, bl, acc, 0, 0, 0);
    }
    {
      int col = nt * 16 + (lane & 15);
      #pragma unroll
      for (int r = 0; r < 4; ++r){
        int row = mt * 16 + ((lane >> 4) << 2) + r;
        if (row < GR) GH[row * NB + col] = acc[r];
      }
    }
    __syncthreads();

    // ---- gate math: one (jj, b) per thread
    {
      const int jj = tid >> 5, b = tid & 31;
      const int jg = j0 + jj;
      float ghr = GH[(0 * HU + jj) * NB + b] + bhh[jg];
      float ghz = GH[(1 * HU + jj) * NB + b] + bhh[NH + jg];
      float ghn = GH[(2 * HU + jj) * NB + b] + bhh[2 * NH + jg];
      const float* gp = gi_t + (size_t)b * 3 * NH;
      float r = 1.f / (1.f + expf(-(gp[jg] + ghr)));
      float z = 1.f / (1.f + expf(-(gp[NH + jg] + ghz)));
      float n = tanhf(gp[2 * NH + jg] + r * ghn);
      int bc2 = (jg * 2) ^ ((b & 7) << 4);
      float hp = bf2f(*(const u16*)((char*)Hhi + ((b << 10) | bc2)))
               + bf2f(*(const u16*)((char*)Hlo + ((b << 10) | bc2)));
      float hnew = (1.f - z) * n + z * hp;
      u16 hi = f2bf(hnew);
      u16 lo = f2bf(hnew - bf2f(hi));
      u16* dh = ((t + 1) & 1) ? HhiG1 : HhiG0;
      u16* dl = ((t + 1) & 1) ? HloG1 : HloG0;
      dh[b * NH + jg] = hi;
      dl[b * NH + jg] = lo;
      if (dec) Hall[((size_t)(t - NS) * NB + b) * NH + jg] = hi;
    }

    if (t == TSTEPS - 1) break;

    // ---- grid barrier (sense-reversing; thread0 fences cover whole wg)
    __syncthreads();
    if (tid == 0){
      unsigned target = ls ^ 1u;
      __builtin_amdgcn_fence(__ATOMIC_RELEASE, "agent");
      unsigned old = __hip_atomic_fetch_add(&bar[0], 1u, __ATOMIC_RELAXED, __HIP_MEMORY_SCOPE_AGENT);
      if (old == RG - 1){
        __hip_atomic_store(&bar[0], 0u, __ATOMIC_RELAXED, __HIP_MEMORY_SCOPE_AGENT);
        __hip_atomic_store(&bar[1], target, __ATOMIC_RELEASE, __HIP_MEMORY_SCOPE_AGENT);
      } else {
        while (__hip_atomic_load(&bar[1], __ATOMIC_RELAXED, __HIP_MEMORY_SCOPE_AGENT) != target)
          __builtin_amdgcn_s_sleep(1);
      }
      __builtin_amdgcn_fence(__ATOMIC_ACQUIRE, "agent");
    }
    ls ^= 1u;
    __syncthreads();

    // ---- stage h for next step from the buffer just written
    {
      const u16* sh = ((t + 1) & 1) ? HhiG1 : HhiG0;
      const u16* sl = ((t + 1) & 1) ? HloG1 : HloG0;
      for (int c = tid; c < NB * 64; c += 256){
        int r = c >> 6, c16 = c & 63;
        int d = (r << 10) | ((c16 * 16) ^ ((r & 7) << 4));
        *(uint4*)((char*)Hhi + d) = *(const uint4*)(sh + (size_t)r * NH + c16 * 8);
        *(uint4*)((char*)Hlo + d) = *(const uint4*)(sl + (size_t)r * NH + c16 * 8);
      }
      __syncthreads();
    }
  }
}

// ---------------------------------------------------------------- launcher
extern "C" void kernel_launch(void* const* d_in, const int* in_sizes, int n_in,
                              void* d_out, int out_size, void* d_ws, size_t ws_size,
                              hipStream_t stream)
{
  const int*   src      = (const int*)  d_in[0];
  const int*   trg      = (const int*)  d_in[1];
  const float* emb_enc  = (const float*)d_in[2];
  const float* W_ih_enc = (const float*)d_in[3];
  const float* W_hh_enc = (const float*)d_in[4];
  const float* b_ih_enc = (const float*)d_in[5];
  const float* b_hh_enc = (const float*)d_in[6];
  const float* emb_dec  = (const float*)d_in[7];
  const float* W_ih_dec = (const float*)d_in[8];
  const float* W_hh_dec = (const float*)d_in[9];
  const float* b_ih_dec = (const float*)d_in[10];
  const float* b_hh_dec = (const float*)d_in[11];
  const float* fc_W     = (const float*)d_in[12];
  const float* fc_b     = (const float*)d_in[13];
  float* out = (float*)d_out;

  char* ws = (char*)d_ws;
  size_t o = 0;
  auto alloc = [&](size_t bytes){ size_t r = o; o += (bytes + 255) & ~(size_t)255; return r; };
  u16*   xenc  = (u16*)(ws + alloc((size_t)2048 * NE * 2));
  u16*   xdec  = (u16*)(ws + alloc((size_t)2048 * NE * 2));   // 2016 used + 32 pad
  u16*   wihe  = (u16*)(ws + alloc((size_t)3 * NH * NE * 2));
  u16*   wihd  = (u16*)(ws + alloc((size_t)3 * NH * NE * 2));
  u16*   fcWbf = (u16*)(ws + alloc((size_t)NV * NH * 2));
  u16*   whiE  = (u16*)(ws + alloc((size_t)3 * NH * NH * 2));
  u16*   wloE  = (u16*)(ws + alloc((size_t)3 * NH * NH * 2));
  u16*   whiD  = (u16*)(ws + alloc((size_t)3 * NH * NH * 2));
  u16*   wloD  = (u16*)(ws + alloc((size_t)3 * NH * NH * 2));
  float* gie   = (float*)(ws + alloc((size_t)2048 * 3 * NH * 4));
  float* gid   = (float*)(ws + alloc((size_t)2048 * 3 * NH * 4));
  u16*   hhi0  = (u16*)(ws + alloc((size_t)NB * NH * 2));
  u16*   hlo0  = (u16*)(ws + alloc((size_t)NB * NH * 2));
  u16*   hhi1  = (u16*)(ws + alloc((size_t)NB * NH * 2));
  u16*   hlo1  = (u16*)(ws + alloc((size_t)NB * NH * 2));
  u16*   Hall  = (u16*)(ws + alloc((size_t)2048 * NH * 2));   // 2016 used + 32 pad
  unsigned* bar = (unsigned*)(ws + alloc(256));

  zero_init<<<256, 256, 0, stream>>>(out, xdec + (size_t)2016 * NE, Hall + (size_t)2016 * NH);
  cvt_f32_bf16<<<384, 256, 0, stream>>>(W_ih_enc, wihe, 3*NH*NE/4);
  cvt_f32_bf16<<<384, 256, 0, stream>>>(W_ih_dec, wihd, 3*NH*NE/4);
  cvt_f32_bf16<<<2048, 256, 0, stream>>>(fc_W, fcWbf, NV*NH/4);
  cvt_hilo<<<1024, 256, 0, stream>>>(W_hh_enc, whiE, wloE, 3*NH*NH);
  cvt_hilo<<<1024, 256, 0, stream>>>(W_hh_dec, whiD, wloD, 3*NH*NH);
  embed_k<<<(NS*NB*64 + 255)/256, 256, 0, stream>>>(src, NS, NS, emb_enc, xenc);
  embed_k<<<((NT-1)*NB*64 + 255)/256, 256, 0, stream>>>(trg, NT, NT-1, emb_dec, xdec);

  // gi = x @ W_ih^T + b_ih   (M=2048, N=1536, K=256) -> grid 12*16 = 192
  gemm_bt<NE, false><<<192, 256, 0, stream>>>(xenc, wihe, b_ih_enc, gie, 2048, 3*NH);
  gemm_bt<NE, false><<<192, 256, 0, stream>>>(xdec, wihd, b_ih_dec, gid, 2048, 3*NH);

  // persistent recurrence
  hipMemsetAsync(bar, 0, 64, stream);
  // LDS: Whi+Wlo (24*512 u16 each) + Hhi+Hlo (32*512 u16 each) + GH (24*32 f32)
  constexpr int SMEM_BYTES = (GR * NH + NB * NH) * 2 /*hi+lo*/ * 2 /*bytes*/ + GR * NB * 4; // 117760
  static_assert(SMEM_BYTES <= 160 * 1024, "LDS over 160 KiB");
  static_assert(SMEM_BYTES == 117760, "unexpected LDS size");
  (void)hipFuncSetAttribute(reinterpret_cast<const void*>(&gru_rec),
                            hipFuncAttributeMaxDynamicSharedMemorySize, SMEM_BYTES);
  gru_rec<<<RG, 256, SMEM_BYTES, stream>>>(whiE, wloE, whiD, wloD, b_hh_enc, b_hh_dec,
                                           gie, gid, hhi0, hlo0, hhi1, hlo1, Hall, bar);

  // logits = h2 @ fc_W^T + fc_b  (M=2048 pad, N=32000, K=512) -> grid 250*16 = 4000
  gemm_bt<NH, true><<<4000, 256, 0, stream>>>(Hall, fcWbf, fc_b, out, 2016, 0);
}